// Round 14
// baseline (1488.982 us; speedup 1.0000x reference)
//
#include <hip/hip_runtime.h>
#include <hip/hip_bf16.h>
#include <math.h>

#define BB 8
#define SS 1024
#define DD 768
#define HH 12
#define LL 6
#define FF 3072
#define CC 10
#define BS_ (BB * SS)   // 8192 rows

// per-layer transposed-weight block (elements)
#define WT_STRIDE (2304 * 768 + 768 * 768 + 3072 * 768 + 768 * 3072)

typedef __attribute__((ext_vector_type(8))) short short8v;       // bf16x8 MFMA frag
typedef __attribute__((ext_vector_type(4))) float f32x4;         // 16x16 MFMA acc
typedef __attribute__((ext_vector_type(8))) unsigned short ushort8v;
typedef __attribute__((ext_vector_type(4))) unsigned short ushort4v;
typedef __attribute__((ext_vector_type(2))) unsigned int uint2v;

#define CEXPQ 0.18033688f   // 0.125 * log2(e), folded into Q at the QKV epilogue

__device__ inline unsigned short f2bf(float f) {
  unsigned int u = __builtin_bit_cast(unsigned int, f);
  u += 0x7fffu + ((u >> 16) & 1u);
  return (unsigned short)(u >> 16);
}
__device__ inline float bf2f(unsigned short u) {
  return __builtin_bit_cast(float, (unsigned int)u << 16);
}
// packed f32x2 -> bf16x2 (RNE) via the HW instruction
__device__ inline unsigned int cvtpk(float lo, float hi) {
  unsigned int r;
  asm("v_cvt_pk_bf16_f32 %0, %1, %2" : "=v"(r) : "v"(lo), "v"(hi));
  return r;
}
__device__ inline void gload16(const void* g, void* l) {
  __builtin_amdgcn_global_load_lds((const __attribute__((address_space(1))) void*)g,
                                   (__attribute__((address_space(3))) void*)l, 16, 0, 0);
}

// ---------------- reduction helpers ----------------
__device__ inline float wave_sum(float v) {
#pragma unroll
  for (int off = 32; off > 0; off >>= 1) v += __shfl_down(v, off);
  return v;
}

// ---------------- embedding + sinusoidal PE (bf16 stream) ----------------
__global__ __launch_bounds__(256) void k_embed(const int* __restrict__ tokens,
                                               const float* __restrict__ emb,
                                               ushort* __restrict__ xb) {
  int row = blockIdx.x;
  int s = row & (SS - 1);
  int tok = tokens[row];
  const float* e = emb + (size_t)tok * DD;
  ushort* xbr = xb + (size_t)row * DD;
  for (int d = threadIdx.x; d < DD; d += 256) {
    float freq = expf((float)(d & ~1) * -0.0119926306f);
    float ang = (float)s * freq;
    float pe = (d & 1) ? cosf(ang) : sinf(ang);
    xbr[d] = f2bf(e[d] + pe);
  }
}

// ---------------- ALL-layer weight transpose: 64x64 tiles, one launch ----------------
__global__ __launch_bounds__(256) void k_transpose_all(
    const float* __restrict__ Wq, const float* __restrict__ Wk,
    const float* __restrict__ Wv, const float* __restrict__ Wo,
    const float* __restrict__ W1, const float* __restrict__ W2,
    ushort* __restrict__ wt) {
  __shared__ float tile[64][65];
  int bid = blockIdx.x;
  int lyr = blockIdx.y;
  ushort* wqkv_t = wt + (size_t)lyr * WT_STRIDE;
  ushort* wo_t = wqkv_t + 2304 * 768;
  ushort* w1_t = wo_t + 768 * 768;
  ushort* w2_t = w1_t + 3072 * 768;
  const float* W; ushort* Wt; int K, N, lb;
  if (bid < 432) {
    int m = bid / 144; lb = bid - m * 144;
    W = ((m == 0) ? Wq : (m == 1) ? Wk : Wv) + (size_t)lyr * DD * DD;
    Wt = wqkv_t + m * 768 * 768; K = 768; N = 768;
  } else if (bid < 576) {
    W = Wo + (size_t)lyr * DD * DD; Wt = wo_t; K = 768; N = 768; lb = bid - 432;
  } else if (bid < 1152) {
    W = W1 + (size_t)lyr * DD * FF; Wt = w1_t; K = 768; N = 3072; lb = bid - 576;
  } else {
    W = W2 + (size_t)lyr * FF * DD; Wt = w2_t; K = 3072; N = 768; lb = bid - 1152;
  }
  int nbk = K >> 6;
  int k0 = (lb % nbk) * 64, n0 = (lb / nbk) * 64;
  int t = threadIdx.x;
  {  // load 64x64 f32 tile, coalesced
    int r = t >> 2, cl = (t & 3) * 16;
    const float* wrow = W + (size_t)(k0 + r) * N + n0 + cl;
#pragma unroll
    for (int j = 0; j < 4; ++j) {
      float4 v = *(const float4*)(wrow + j * 4);
      tile[r][cl + j * 4 + 0] = v.x; tile[r][cl + j * 4 + 1] = v.y;
      tile[r][cl + j * 4 + 2] = v.z; tile[r][cl + j * 4 + 3] = v.w;
    }
  }
  __syncthreads();
  {  // write transposed bf16
    int n = t >> 2, cq = (t & 3) * 16;
    ushort8v o0, o1;
#pragma unroll
    for (int jj = 0; jj < 8; ++jj) o0[jj] = f2bf(tile[cq + jj][n]);
#pragma unroll
    for (int jj = 0; jj < 8; ++jj) o1[jj] = f2bf(tile[cq + 8 + jj][n]);
    ushort* orow = Wt + (size_t)(n0 + n) * K + k0 + cq;
    *(ushort8v*)(orow) = o0;
    *(ushort8v*)(orow + 8) = o1;
  }
}

// ---------------- bf16 MFMA GEMM: dbuf + counted vmcnt (T3/T4), T2 swizzle ----------------
template <int RELU, int TN, int SCALEQ = 0>
__global__ __launch_bounds__(256) void k_gemm_db(const ushort* __restrict__ A,
                                                 const ushort* __restrict__ Bt,
                                                 ushort* __restrict__ Cout,
                                                 int M, int N, int K) {
  constexpr int NF = TN / 32;            // B frags per wave
  __shared__ ushort smem[2][(128 + TN) * 64];
  int bidl = blockIdx.y * gridDim.x + blockIdx.x;
  int nwg = gridDim.x * gridDim.y;
  int cpx = nwg >> 3;
  int tid = (bidl & 7) * cpx + (bidl >> 3);
  int n0 = (tid % gridDim.x) * TN, m0 = (tid / gridDim.x) * 128;
  int t = threadIdx.x, w = t >> 6, l = t & 63;
  int wr = (w >> 1) * 64, wc = (w & 1) * (TN / 2);
  int lr = l & 15, lg = l >> 4;
  f32x4 acc[4][NF] = {};
  int sr8 = l >> 3;
  int scw = ((l & 7) ^ sr8) * 8;          // inverse-swizzled source col
  const ushort* ag = A + (size_t)(m0 + w * 8 + sr8) * K + scw;
  const ushort* bg = Bt + (size_t)(n0 + w * 8 + sr8) * K + scw;
  int nk = K >> 6;

#define STAGE_TILE(KC0, BUF)                                                     \
  {                                                                              \
    ushort* al = &smem[BUF][(w * 8) * 64];                                       \
    ushort* bl = &smem[BUF][128 * 64 + (w * 8) * 64];                            \
    _Pragma("unroll") for (int ii = 0; ii < 4; ++ii)                             \
        gload16(ag + (size_t)ii * 32 * K + (KC0), al + ii * 2048);               \
    _Pragma("unroll") for (int ii = 0; ii < TN / 32; ++ii)                       \
        gload16(bg + (size_t)ii * 32 * K + (KC0), bl + ii * 2048);               \
  }

  STAGE_TILE(0, 0);
  if (nk > 1) STAGE_TILE(64, 1);
  int rsw = lr & 7;
  for (int k = 0; k < nk; ++k) {
    if (k + 1 < nk) {
      if constexpr (TN == 128) asm volatile("s_waitcnt vmcnt(8)" ::: "memory");
      else                     asm volatile("s_waitcnt vmcnt(6)" ::: "memory");
    } else {
      asm volatile("s_waitcnt vmcnt(0)" ::: "memory");
    }
    __builtin_amdgcn_s_barrier();
    __builtin_amdgcn_sched_barrier(0);
    const ushort* As = &smem[k & 1][0];
    const ushort* Bs = &smem[k & 1][128 * 64];
    short8v af[2][4], bfr[2][NF];
#pragma unroll
    for (int ks = 0; ks < 2; ++ks) {
#pragma unroll
      for (int mi = 0; mi < 4; ++mi)
        af[ks][mi] = *(const short8v*)(As + (wr + mi * 16 + lr) * 64 + (((ks * 4 + lg) ^ rsw) << 3));
#pragma unroll
      for (int ni = 0; ni < NF; ++ni)
        bfr[ks][ni] = *(const short8v*)(Bs + (wc + ni * 16 + lr) * 64 + (((ks * 4 + lg) ^ rsw) << 3));
    }
    asm volatile("s_waitcnt lgkmcnt(0)" ::: "memory");
    __builtin_amdgcn_s_barrier();        // all waves' frag reads done: buffer free
    __builtin_amdgcn_sched_barrier(0);
    if (k + 2 < nk) STAGE_TILE((k + 2) * 64, k & 1);
    __builtin_amdgcn_s_setprio(1);
#pragma unroll
    for (int ks = 0; ks < 2; ++ks)
#pragma unroll
      for (int mi = 0; mi < 4; ++mi)
#pragma unroll
        for (int ni = 0; ni < NF; ++ni)
          acc[mi][ni] = __builtin_amdgcn_mfma_f32_16x16x32_bf16(af[ks][mi], bfr[ks][ni], acc[mi][ni], 0, 0, 0);
    __builtin_amdgcn_s_setprio(0);
  }
#undef STAGE_TILE
  __syncthreads();
  float osc = (SCALEQ && n0 < 768) ? CEXPQ : 1.0f;
  ushort* cst = &smem[0][0];
#pragma unroll
  for (int mi = 0; mi < 4; ++mi)
#pragma unroll
    for (int ni = 0; ni < NF; ++ni) {
      int cl = wc + ni * 16 + lr;
#pragma unroll
      for (int i = 0; i < 4; ++i) {
        int rl = wr + mi * 16 + lg * 4 + i;
        float v = acc[mi][ni][i];
        if (RELU) v = fmaxf(v, 0.f);
        if (SCALEQ) v *= osc;
        cst[rl * TN + (cl ^ (((rl >> 2) & 3) << 4))] = f2bf(v);
      }
    }
  __syncthreads();
  {
    int row = t >> 1, half = t & 1;
    int swr = ((row >> 2) & 3) << 4;
    ushort* crow = Cout + (size_t)(m0 + row) * N + n0 + half * (TN / 2);
#pragma unroll
    for (int c8 = 0; c8 < TN / 16; ++c8) {
      int c = half * (TN / 2) + c8 * 8;
      ushort8v vv = *(const ushort8v*)(&cst[row * TN + (c ^ swr)]);
      *(ushort8v*)(crow + c8 * 8) = vv;
    }
  }
}

// ---------------- flash attention: 16x16 MFMA, DOUBLE-BUFFERED K/V, 1 barrier/tile ----------------
// r11 compute core (verified fragment/swizzle formulas) with T3-style staging:
// at top of iter kt, issue K(kt+1)->Ks[nxt] (gload_lds) and V(kt+1)->regs;
// compute tile kt from [cur]; write Vt[nxt] at the end; ONE barrier.
// Both load streams get the whole compute phase to fly.
__global__ __launch_bounds__(256) void k_flash(const ushort* __restrict__ qkv,
                                               ushort* __restrict__ ao) {
  __shared__ ushort Ks[2][64][64];
  __shared__ ushort Vt[2][64][64];
  __shared__ ushort Ps[4][32][64];
  const int LD = 2304;
  int bidl = blockIdx.y * gridDim.x + blockIdx.x;   // grid 8 x 96 = 768
  int tid = (bidl & 7) * 96 + (bidl >> 3);
  int qt = tid & 7;
  int bh = tid >> 3;
  int h = bh % HH, b = bh / HH;
  int t = threadIdx.x, w = t >> 6, l = t & 63;
  int lr = l & 15, lg = l >> 4;
  int sw = (l & 7) << 3;
  int q0 = qt * 128;
  const ushort* qbase = qkv + (size_t)(b * SS) * LD + h * 64;
  const ushort* kbase = qbase + 768;
  const ushort* vbase = qbase + 1536;
  short8v qf[2][2];
#pragma unroll
  for (int qg = 0; qg < 2; ++qg) {
    const ushort* qrow = qbase + (size_t)(q0 + w * 32 + qg * 16 + lr) * LD + lg * 8;
    qf[qg][0] = *(const short8v*)(qrow);
    qf[qg][1] = *(const short8v*)(qrow + 32);
  }
  float l_run[2] = {0.f, 0.f};
  f32x4 o_acc[2][4] = {};
  int krow_ = w * 16 + (l >> 3);
  int kcol_ = ((l & 7) * 8) ^ ((krow_ & 7) << 3);
  const ushort* kg = kbase + (size_t)krow_ * LD + kcol_;
  int d_ = t & 7;
  int dk0 = d_ * 8;
  int kv2 = (t >> 3) * 2;
  const ushort* vg = vbase + (size_t)kv2 * LD + dk0;
  {  // prologue: stage tile 0 (K->Ks[0], V->regs->Vt[0])
    gload16(kg, &Ks[0][w * 16][0]);
    gload16(kg + (size_t)8 * LD, &Ks[0][w * 16 + 8][0]);
    ushort8v v0 = *(const ushort8v*)(vg);
    ushort8v v1 = *(const ushort8v*)(vg + LD);
#pragma unroll
    for (int i = 0; i < 8; ++i) {
      unsigned int pack = (unsigned int)v0[i] | ((unsigned int)v1[i] << 16);
      *(unsigned int*)(&Vt[0][dk0 + i][kv2 ^ (((i ^ d_) & 7) << 3)]) = pack;
    }
    __syncthreads();   // drains K(0) gload + Vt[0] writes
  }
  for (int kt = 0; kt < 16; ++kt) {
    int cur = kt & 1, nxt = cur ^ 1;
    ushort8v v0n, v1n;
    if (kt < 15) {     // issue next tile's loads; they fly during compute(kt)
      size_t off = (size_t)(kt + 1) * 64 * LD;
      gload16(kg + off, &Ks[nxt][w * 16][0]);
      gload16(kg + off + (size_t)8 * LD, &Ks[nxt][w * 16 + 8][0]);
      v0n = *(const ushort8v*)(vg + off);
      v1n = *(const ushort8v*)(vg + off + LD);
    }
    short8v kf[4][2];
#pragma unroll
    for (int mi = 0; mi < 4; ++mi) {
      int kvr = mi * 16 + lr;
      kf[mi][0] = *(const short8v*)(&Ks[cur][kvr][(lg * 8) ^ sw]);
      kf[mi][1] = *(const short8v*)(&Ks[cur][kvr][(32 + lg * 8) ^ sw]);
    }
    f32x4 s[2][4] = {};
    __builtin_amdgcn_s_setprio(1);
#pragma unroll
    for (int mi = 0; mi < 4; ++mi)
#pragma unroll
      for (int qg = 0; qg < 2; ++qg) {
        s[qg][mi] = __builtin_amdgcn_mfma_f32_16x16x32_bf16(kf[mi][0], qf[qg][0], s[qg][mi], 0, 0, 0);
        s[qg][mi] = __builtin_amdgcn_mfma_f32_16x16x32_bf16(kf[mi][1], qf[qg][1], s[qg][mi], 0, 0, 0);
      }
    __builtin_amdgcn_s_setprio(0);
#pragma unroll
    for (int qg = 0; qg < 2; ++qg) {
      float psum = 0.f;
#pragma unroll
      for (int mi = 0; mi < 4; ++mi) {
        float p0 = exp2f(s[qg][mi][0]);
        float p1 = exp2f(s[qg][mi][1]);
        float p2 = exp2f(s[qg][mi][2]);
        float p3 = exp2f(s[qg][mi][3]);
        psum += (p0 + p1) + (p2 + p3);
        uint2v pp;
        pp.x = cvtpk(p0, p1);
        pp.y = cvtpk(p2, p3);
        *(uint2v*)(&Ps[w][qg * 16 + lr][(mi * 16 + lg * 4) ^ ((lr & 7) << 3)]) = pp;
      }
      psum += __shfl_xor(psum, 16);
      psum += __shfl_xor(psum, 32);
      l_run[qg] += psum;
    }
#pragma unroll
    for (int ks = 0; ks < 2; ++ks) {
      short8v pf[2];
      pf[0] = *(const short8v*)(&Ps[w][lr][(ks * 32 + lg * 8) ^ sw]);
      pf[1] = *(const short8v*)(&Ps[w][16 + lr][(ks * 32 + lg * 8) ^ sw]);
      short8v vf[4];
#pragma unroll
      for (int mi = 0; mi < 4; ++mi) {
        int swz = ((lr & 7) ^ (mi * 2 + (lr >> 3))) & 7;
        vf[mi] = *(const short8v*)(&Vt[cur][mi * 16 + lr][(ks * 32 + lg * 8) ^ (swz << 3)]);
      }
      __builtin_amdgcn_s_setprio(1);
#pragma unroll
      for (int mi = 0; mi < 4; ++mi)
#pragma unroll
        for (int qg = 0; qg < 2; ++qg)
          o_acc[qg][mi] = __builtin_amdgcn_mfma_f32_16x16x32_bf16(vf[mi], pf[qg], o_acc[qg][mi], 0, 0, 0);
      __builtin_amdgcn_s_setprio(0);
    }
    if (kt < 15) {     // write next V tile (v-regs had the whole compute to land)
#pragma unroll
      for (int i = 0; i < 8; ++i) {
        unsigned int pack = (unsigned int)v0n[i] | ((unsigned int)v1n[i] << 16);
        *(unsigned int*)(&Vt[nxt][dk0 + i][kv2 ^ (((i ^ d_) & 7) << 3)]) = pack;
      }
    }
    __syncthreads();   // single barrier: drains K gload (flew during compute) + Vt writes
  }
#pragma unroll
  for (int qg = 0; qg < 2; ++qg) {
    float invl = 1.f / l_run[qg];
    ushort* orow = ao + (size_t)(b * SS + q0 + w * 32 + qg * 16 + lr) * DD + h * 64;
#pragma unroll
    for (int mi = 0; mi < 4; ++mi) {
      ushort4v o;
#pragma unroll
      for (int i = 0; i < 4; ++i) o[i] = f2bf(o_acc[qg][mi][i] * invl);
      *(ushort4v*)(orow + mi * 16 + lg * 4) = o;
    }
  }
}

// ---------------- residual add + layernorm (pure bf16 stream, 1 wave/row) ----------------
__global__ __launch_bounds__(64) void k_addln(ushort* __restrict__ xb,
                                              const ushort* __restrict__ y,
                                              const float* __restrict__ sc,
                                              const float* __restrict__ bi) {
  int row = blockIdx.x, l = threadIdx.x;
  int d0 = l * 12;
  ushort* xr = xb + (size_t)row * DD;
  const ushort* yr = y + (size_t)row * DD;
  ushort4v xa[3], ya[3];
#pragma unroll
  for (int j = 0; j < 3; ++j) {
    xa[j] = *(const ushort4v*)(xr + d0 + j * 4);
    ya[j] = *(const ushort4v*)(yr + d0 + j * 4);
  }
  float v[12];
  float s = 0.f;
#pragma unroll
  for (int j = 0; j < 3; ++j)
#pragma unroll
    for (int i = 0; i < 4; ++i) {
      float vv = bf2f(xa[j][i]) + bf2f(ya[j][i]);
      v[j * 4 + i] = vv;
      s += vv;
    }
  float mu = wave_sum(s);
  mu = __shfl(mu, 0) * (1.f / 768.f);
  float vs = 0.f;
#pragma unroll
  for (int i = 0; i < 12; ++i) {
    float c = v[i] - mu;
    vs += c * c;
  }
  vs = wave_sum(vs);
  float rstd = rsqrtf(__shfl(vs, 0) * (1.f / 768.f) + 1e-5f);
  float4 scv[3], biv[3];
#pragma unroll
  for (int j = 0; j < 3; ++j) {
    scv[j] = *(const float4*)(sc + d0 + j * 4);
    biv[j] = *(const float4*)(bi + d0 + j * 4);
  }
#pragma unroll
  for (int j = 0; j < 3; ++j) {
    ushort4v o;
    const float* sj = (const float*)&scv[j];
    const float* bj = (const float*)&biv[j];
#pragma unroll
    for (int i = 0; i < 4; ++i) o[i] = f2bf((v[j * 4 + i] - mu) * rstd * sj[i] + bj[i]);
    *(ushort4v*)(xr + d0 + j * 4) = o;
  }
}

// ---------------- mean pool + classifier ----------------
__global__ __launch_bounds__(256) void k_pool(const ushort* __restrict__ xb,
                                              float* __restrict__ pooled) {
  int b = blockIdx.x, chunk = blockIdx.y, t = threadIdx.x;
  float a0 = 0, a1 = 0, a2 = 0;
  for (int s2 = chunk * 128; s2 < chunk * 128 + 128; ++s2) {
    const ushort* xr = xb + (size_t)(b * SS + s2) * DD;
    a0 += bf2f(xr[t]); a1 += bf2f(xr[t + 256]); a2 += bf2f(xr[t + 512]);
  }
  atomicAdd(&pooled[b * DD + t], a0 * (1.f / 1024.f));
  atomicAdd(&pooled[b * DD + t + 256], a1 * (1.f / 1024.f));
  atomicAdd(&pooled[b * DD + t + 512], a2 * (1.f / 1024.f));
}

__global__ __launch_bounds__(64) void k_cls(const float* __restrict__ pooled,
                                            const float* __restrict__ Wc,
                                            const float* __restrict__ bc,
                                            float* __restrict__ out) {
  int idx = blockIdx.x;
  int b = idx / CC, c = idx % CC;
  int t = threadIdx.x;
  float acc = 0.f;
  for (int d0 = t; d0 < DD; d0 += 64) acc = fmaf(pooled[b * DD + d0], Wc[d0 * CC + c], acc);
  acc = wave_sum(acc);
  if (t == 0) out[b * CC + c] = acc + bc[c];
}

extern "C" void kernel_launch(void* const* d_in, const int* in_sizes, int n_in,
                              void* d_out, int out_size, void* d_ws, size_t ws_size,
                              hipStream_t stream) {
  (void)in_sizes; (void)n_in; (void)out_size; (void)ws_size;
  const int* tokens = (const int*)d_in[0];
  const float* emb = (const float*)d_in[1];
  const float* Wq = (const float*)d_in[2];
  const float* Wk = (const float*)d_in[3];
  const float* Wv = (const float*)d_in[4];
  const float* Wo = (const float*)d_in[5];
  const float* W1 = (const float*)d_in[6];
  const float* W2 = (const float*)d_in[7];
  const float* l1s = (const float*)d_in[8];
  const float* l1b = (const float*)d_in[9];
  const float* l2s = (const float*)d_in[10];
  const float* l2b = (const float*)d_in[11];
  const float* Wc = (const float*)d_in[12];
  const float* bc = (const float*)d_in[13];
  float* out = (float*)d_out;

  char* p = (char*)d_ws;
  ushort* xb = (ushort*)p;              p += (size_t)BS_ * DD * 2;
  ushort* qkvb = (ushort*)p;            // [8192][2304]
  ushort* hb = (ushort*)p;              // [8192][3072] overlay
  ushort* ao = (ushort*)(p + (size_t)BS_ * 2304 * 2);
  p += (size_t)BS_ * FF * 2;
  ushort* yb = (ushort*)p;              p += (size_t)BS_ * DD * 2;
  ushort* wt = (ushort*)p;              p += (size_t)WT_STRIDE * LL * 2;   // all 6 layers
  float* pooled = (float*)p;

  k_embed<<<BS_, 256, 0, stream>>>(tokens, emb, xb);
  k_transpose_all<<<dim3(1728, LL), 256, 0, stream>>>(Wq, Wk, Wv, Wo, W1, W2, wt);

  for (int l = 0; l < LL; ++l) {
    ushort* wqkv_t = wt + (size_t)l * WT_STRIDE;   // [2304][768]
    ushort* wo_t = wqkv_t + 2304 * 768;            // [768][768]
    ushort* w1_t = wo_t + 768 * 768;               // [3072][768]
    ushort* w2_t = w1_t + 3072 * 768;              // [768][3072]

    k_gemm_db<0, 128, 1><<<dim3(2304 / 128, BS_ / 128), 256, 0, stream>>>(xb, wqkv_t, qkvb, BS_, 2304, DD);
    k_flash<<<dim3(8, BB * HH), 256, 0, stream>>>(qkvb, ao);
    k_gemm_db<0, 64><<<dim3(DD / 64, BS_ / 128), 256, 0, stream>>>(ao, wo_t, yb, BS_, DD, DD);
    k_addln<<<BS_, 64, 0, stream>>>(xb, yb, l1s + l * DD, l1b + l * DD);
    k_gemm_db<1, 128><<<dim3(FF / 128, BS_ / 128), 256, 0, stream>>>(xb, w1_t, hb, BS_, FF, DD);
    k_gemm_db<0, 64><<<dim3(DD / 64, BS_ / 128), 256, 0, stream>>>(hb, w2_t, yb, BS_, DD, FF);
    k_addln<<<BS_, 64, 0, stream>>>(xb, yb, l2s + l * DD, l2b + l * DD);
  }

  hipMemsetAsync(pooled, 0, (size_t)BB * DD * sizeof(float), stream);
  k_pool<<<dim3(BB, 8), 256, 0, stream>>>(xb, pooled);
  k_cls<<<BB * CC, 64, 0, stream>>>(pooled, Wc, bc, out);
}

// Round 15
// 1430.320 us; speedup vs baseline: 1.0410x; 1.0410x over previous
//
#include <hip/hip_runtime.h>
#include <hip/hip_bf16.h>
#include <math.h>

#define BB 8
#define SS 1024
#define DD 768
#define HH 12
#define LL 6
#define FF 3072
#define CC 10
#define BS_ (BB * SS)   // 8192 rows

// per-layer transposed-weight block (elements)
#define WT_STRIDE (2304 * 768 + 768 * 768 + 3072 * 768 + 768 * 3072)

typedef __attribute__((ext_vector_type(8))) short short8v;       // bf16x8 MFMA frag
typedef __attribute__((ext_vector_type(4))) float f32x4;         // 16x16 MFMA acc
typedef __attribute__((ext_vector_type(8))) unsigned short ushort8v;
typedef __attribute__((ext_vector_type(4))) unsigned short ushort4v;
typedef __attribute__((ext_vector_type(2))) unsigned int uint2v;

#define CEXPQ 0.18033688f   // 0.125 * log2(e), folded into Q at the QKV epilogue

__device__ inline unsigned short f2bf(float f) {
  unsigned int u = __builtin_bit_cast(unsigned int, f);
  u += 0x7fffu + ((u >> 16) & 1u);
  return (unsigned short)(u >> 16);
}
__device__ inline float bf2f(unsigned short u) {
  return __builtin_bit_cast(float, (unsigned int)u << 16);
}
// packed f32x2 -> bf16x2 (RNE) via the HW instruction
__device__ inline unsigned int cvtpk(float lo, float hi) {
  unsigned int r;
  asm("v_cvt_pk_bf16_f32 %0, %1, %2" : "=v"(r) : "v"(lo), "v"(hi));
  return r;
}
__device__ inline void gload16(const void* g, void* l) {
  __builtin_amdgcn_global_load_lds((const __attribute__((address_space(1))) void*)g,
                                   (__attribute__((address_space(3))) void*)l, 16, 0, 0);
}

// ---------------- reduction helpers ----------------
__device__ inline float wave_sum(float v) {
#pragma unroll
  for (int off = 32; off > 0; off >>= 1) v += __shfl_down(v, off);
  return v;
}

// ---------------- embedding + sinusoidal PE (bf16 stream) ----------------
__global__ __launch_bounds__(256) void k_embed(const int* __restrict__ tokens,
                                               const float* __restrict__ emb,
                                               ushort* __restrict__ xb) {
  int row = blockIdx.x;
  int s = row & (SS - 1);
  int tok = tokens[row];
  const float* e = emb + (size_t)tok * DD;
  ushort* xbr = xb + (size_t)row * DD;
  for (int d = threadIdx.x; d < DD; d += 256) {
    float freq = expf((float)(d & ~1) * -0.0119926306f);
    float ang = (float)s * freq;
    float pe = (d & 1) ? cosf(ang) : sinf(ang);
    xbr[d] = f2bf(e[d] + pe);
  }
}

// ---------------- ALL-layer weight transpose: 64x64 tiles, one launch ----------------
__global__ __launch_bounds__(256) void k_transpose_all(
    const float* __restrict__ Wq, const float* __restrict__ Wk,
    const float* __restrict__ Wv, const float* __restrict__ Wo,
    const float* __restrict__ W1, const float* __restrict__ W2,
    ushort* __restrict__ wt) {
  __shared__ float tile[64][65];
  int bid = blockIdx.x;
  int lyr = blockIdx.y;
  ushort* wqkv_t = wt + (size_t)lyr * WT_STRIDE;
  ushort* wo_t = wqkv_t + 2304 * 768;
  ushort* w1_t = wo_t + 768 * 768;
  ushort* w2_t = w1_t + 3072 * 768;
  const float* W; ushort* Wt; int K, N, lb;
  if (bid < 432) {
    int m = bid / 144; lb = bid - m * 144;
    W = ((m == 0) ? Wq : (m == 1) ? Wk : Wv) + (size_t)lyr * DD * DD;
    Wt = wqkv_t + m * 768 * 768; K = 768; N = 768;
  } else if (bid < 576) {
    W = Wo + (size_t)lyr * DD * DD; Wt = wo_t; K = 768; N = 768; lb = bid - 432;
  } else if (bid < 1152) {
    W = W1 + (size_t)lyr * DD * FF; Wt = w1_t; K = 768; N = 3072; lb = bid - 576;
  } else {
    W = W2 + (size_t)lyr * FF * DD; Wt = w2_t; K = 3072; N = 768; lb = bid - 1152;
  }
  int nbk = K >> 6;
  int k0 = (lb % nbk) * 64, n0 = (lb / nbk) * 64;
  int t = threadIdx.x;
  {  // load 64x64 f32 tile, coalesced
    int r = t >> 2, cl = (t & 3) * 16;
    const float* wrow = W + (size_t)(k0 + r) * N + n0 + cl;
#pragma unroll
    for (int j = 0; j < 4; ++j) {
      float4 v = *(const float4*)(wrow + j * 4);
      tile[r][cl + j * 4 + 0] = v.x; tile[r][cl + j * 4 + 1] = v.y;
      tile[r][cl + j * 4 + 2] = v.z; tile[r][cl + j * 4 + 3] = v.w;
    }
  }
  __syncthreads();
  {  // write transposed bf16
    int n = t >> 2, cq = (t & 3) * 16;
    ushort8v o0, o1;
#pragma unroll
    for (int jj = 0; jj < 8; ++jj) o0[jj] = f2bf(tile[cq + jj][n]);
#pragma unroll
    for (int jj = 0; jj < 8; ++jj) o1[jj] = f2bf(tile[cq + 8 + jj][n]);
    ushort* orow = Wt + (size_t)(n0 + n) * K + k0 + cq;
    *(ushort8v*)(orow) = o0;
    *(ushort8v*)(orow + 8) = o1;
  }
}

// ---------------- bf16 MFMA GEMM: dbuf + counted vmcnt (T3/T4), T2 swizzle ----------------
template <int RELU, int TN, int SCALEQ = 0>
__global__ __launch_bounds__(256) void k_gemm_db(const ushort* __restrict__ A,
                                                 const ushort* __restrict__ Bt,
                                                 ushort* __restrict__ Cout,
                                                 int M, int N, int K) {
  constexpr int NF = TN / 32;            // B frags per wave
  __shared__ ushort smem[2][(128 + TN) * 64];
  int bidl = blockIdx.y * gridDim.x + blockIdx.x;
  int nwg = gridDim.x * gridDim.y;
  int cpx = nwg >> 3;
  int tid = (bidl & 7) * cpx + (bidl >> 3);
  int n0 = (tid % gridDim.x) * TN, m0 = (tid / gridDim.x) * 128;
  int t = threadIdx.x, w = t >> 6, l = t & 63;
  int wr = (w >> 1) * 64, wc = (w & 1) * (TN / 2);
  int lr = l & 15, lg = l >> 4;
  f32x4 acc[4][NF] = {};
  int sr8 = l >> 3;
  int scw = ((l & 7) ^ sr8) * 8;          // inverse-swizzled source col
  const ushort* ag = A + (size_t)(m0 + w * 8 + sr8) * K + scw;
  const ushort* bg = Bt + (size_t)(n0 + w * 8 + sr8) * K + scw;
  int nk = K >> 6;

#define STAGE_TILE(KC0, BUF)                                                     \
  {                                                                              \
    ushort* al = &smem[BUF][(w * 8) * 64];                                       \
    ushort* bl = &smem[BUF][128 * 64 + (w * 8) * 64];                            \
    _Pragma("unroll") for (int ii = 0; ii < 4; ++ii)                             \
        gload16(ag + (size_t)ii * 32 * K + (KC0), al + ii * 2048);               \
    _Pragma("unroll") for (int ii = 0; ii < TN / 32; ++ii)                       \
        gload16(bg + (size_t)ii * 32 * K + (KC0), bl + ii * 2048);               \
  }

  STAGE_TILE(0, 0);
  if (nk > 1) STAGE_TILE(64, 1);
  int rsw = lr & 7;
  for (int k = 0; k < nk; ++k) {
    if (k + 1 < nk) {
      if constexpr (TN == 128) asm volatile("s_waitcnt vmcnt(8)" ::: "memory");
      else                     asm volatile("s_waitcnt vmcnt(6)" ::: "memory");
    } else {
      asm volatile("s_waitcnt vmcnt(0)" ::: "memory");
    }
    __builtin_amdgcn_s_barrier();
    __builtin_amdgcn_sched_barrier(0);
    const ushort* As = &smem[k & 1][0];
    const ushort* Bs = &smem[k & 1][128 * 64];
    short8v af[2][4], bfr[2][NF];
#pragma unroll
    for (int ks = 0; ks < 2; ++ks) {
#pragma unroll
      for (int mi = 0; mi < 4; ++mi)
        af[ks][mi] = *(const short8v*)(As + (wr + mi * 16 + lr) * 64 + (((ks * 4 + lg) ^ rsw) << 3));
#pragma unroll
      for (int ni = 0; ni < NF; ++ni)
        bfr[ks][ni] = *(const short8v*)(Bs + (wc + ni * 16 + lr) * 64 + (((ks * 4 + lg) ^ rsw) << 3));
    }
    asm volatile("s_waitcnt lgkmcnt(0)" ::: "memory");
    __builtin_amdgcn_s_barrier();        // all waves' frag reads done: buffer free
    __builtin_amdgcn_sched_barrier(0);
    if (k + 2 < nk) STAGE_TILE((k + 2) * 64, k & 1);
    __builtin_amdgcn_s_setprio(1);
#pragma unroll
    for (int ks = 0; ks < 2; ++ks)
#pragma unroll
      for (int mi = 0; mi < 4; ++mi)
#pragma unroll
        for (int ni = 0; ni < NF; ++ni)
          acc[mi][ni] = __builtin_amdgcn_mfma_f32_16x16x32_bf16(af[ks][mi], bfr[ks][ni], acc[mi][ni], 0, 0, 0);
    __builtin_amdgcn_s_setprio(0);
  }
#undef STAGE_TILE
  __syncthreads();
  float osc = (SCALEQ && n0 < 768) ? CEXPQ : 1.0f;
  ushort* cst = &smem[0][0];
#pragma unroll
  for (int mi = 0; mi < 4; ++mi)
#pragma unroll
    for (int ni = 0; ni < NF; ++ni) {
      int cl = wc + ni * 16 + lr;
#pragma unroll
      for (int i = 0; i < 4; ++i) {
        int rl = wr + mi * 16 + lg * 4 + i;
        float v = acc[mi][ni][i];
        if (RELU) v = fmaxf(v, 0.f);
        if (SCALEQ) v *= osc;
        cst[rl * TN + (cl ^ (((rl >> 2) & 3) << 4))] = f2bf(v);
      }
    }
  __syncthreads();
  {
    int row = t >> 1, half = t & 1;
    int swr = ((row >> 2) & 3) << 4;
    ushort* crow = Cout + (size_t)(m0 + row) * N + n0 + half * (TN / 2);
#pragma unroll
    for (int c8 = 0; c8 < TN / 16; ++c8) {
      int c = half * (TN / 2) + c8 * 8;
      ushort8v vv = *(const ushort8v*)(&cst[row * TN + (c ^ swr)]);
      *(ushort8v*)(crow + c8 * 8) = vv;
    }
  }
}

// ---------------- flash attention: 16x16 MFMA, Q-tile 64, KV-tile 64 ----------------
// r12 single-buffer core (measured 65 us) with HALVED Q-tile: 4 waves x 16
// q-rows, grid 16x96 = 1536 blocks = 6/CU all-resident (24 KB LDS, ~60 VGPR).
// Doubles independent progress groups per CU; halves per-wave serial chain.
__global__ __launch_bounds__(256) void k_flash(const ushort* __restrict__ qkv,
                                               ushort* __restrict__ ao) {
  __shared__ ushort Ks[64][64];
  __shared__ ushort Vt[64][64];
  __shared__ ushort Ps[4][16][64];
  const int LD = 2304;
  int bidl = blockIdx.y * gridDim.x + blockIdx.x;   // grid 16 x 96 = 1536
  int tid = (bidl & 7) * 192 + (bidl >> 3);
  int qt = tid & 15;
  int bh = tid >> 4;                 // 12 bh per XCD chunk -> KV L2 locality
  int h = bh % HH, b = bh / HH;
  int t = threadIdx.x, w = t >> 6, l = t & 63;
  int lr = l & 15, lg = l >> 4;
  int sw = (l & 7) << 3;
  int q0 = qt * 64;
  const ushort* qbase = qkv + (size_t)(b * SS) * LD + h * 64;
  const ushort* kbase = qbase + 768;
  const ushort* vbase = qbase + 1536;
  short8v qf[2];
  {
    const ushort* qrow = qbase + (size_t)(q0 + w * 16 + lr) * LD + lg * 8;
    qf[0] = *(const short8v*)(qrow);
    qf[1] = *(const short8v*)(qrow + 32);
  }
  float l_run = 0.f;
  f32x4 o_acc[4] = {};
  int krow_ = w * 16 + (l >> 3);
  int kcol_ = ((l & 7) * 8) ^ ((krow_ & 7) << 3);
  const ushort* kg = kbase + (size_t)krow_ * LD + kcol_;
  ushort* kl = &Ks[w * 16][0];
  int d_ = t & 7;
  int dk0 = d_ * 8;
  int kv2 = (t >> 3) * 2;
  for (int kt = 0; kt < 16; ++kt) {
    int kv0 = kt * 64;
    const ushort* vr0 = vbase + (size_t)(kv0 + kv2) * LD + dk0;
    ushort8v v0 = *(const ushort8v*)(vr0);
    ushort8v v1 = *(const ushort8v*)(vr0 + LD);
    __syncthreads();
    gload16(kg + (size_t)kv0 * LD, kl);
    gload16(kg + (size_t)(kv0 + 8) * LD, kl + 512);
#pragma unroll
    for (int i = 0; i < 8; ++i) {
      unsigned int pack = (unsigned int)v0[i] | ((unsigned int)v1[i] << 16);
      *(unsigned int*)(&Vt[dk0 + i][kv2 ^ (((i ^ d_) & 7) << 3)]) = pack;
    }
    __syncthreads();
    short8v kf[4][2];
#pragma unroll
    for (int mi = 0; mi < 4; ++mi) {
      int kvr = mi * 16 + lr;
      kf[mi][0] = *(const short8v*)(&Ks[kvr][(lg * 8) ^ sw]);
      kf[mi][1] = *(const short8v*)(&Ks[kvr][(32 + lg * 8) ^ sw]);
    }
    f32x4 s[4] = {};
    __builtin_amdgcn_s_setprio(1);
#pragma unroll
    for (int mi = 0; mi < 4; ++mi) {
      s[mi] = __builtin_amdgcn_mfma_f32_16x16x32_bf16(kf[mi][0], qf[0], s[mi], 0, 0, 0);
      s[mi] = __builtin_amdgcn_mfma_f32_16x16x32_bf16(kf[mi][1], qf[1], s[mi], 0, 0, 0);
    }
    __builtin_amdgcn_s_setprio(0);
    {
      float psum = 0.f;
#pragma unroll
      for (int mi = 0; mi < 4; ++mi) {
        float p0 = exp2f(s[mi][0]);
        float p1 = exp2f(s[mi][1]);
        float p2 = exp2f(s[mi][2]);
        float p3 = exp2f(s[mi][3]);
        psum += (p0 + p1) + (p2 + p3);
        uint2v pp;
        pp.x = cvtpk(p0, p1);
        pp.y = cvtpk(p2, p3);
        *(uint2v*)(&Ps[w][lr][(mi * 16 + lg * 4) ^ ((lr & 7) << 3)]) = pp;
      }
      psum += __shfl_xor(psum, 16);
      psum += __shfl_xor(psum, 32);
      l_run += psum;
    }
#pragma unroll
    for (int ks = 0; ks < 2; ++ks) {
      short8v pf = *(const short8v*)(&Ps[w][lr][(ks * 32 + lg * 8) ^ sw]);
      short8v vf[4];
#pragma unroll
      for (int mi = 0; mi < 4; ++mi) {
        int swz = ((lr & 7) ^ (mi * 2 + (lr >> 3))) & 7;
        vf[mi] = *(const short8v*)(&Vt[mi * 16 + lr][(ks * 32 + lg * 8) ^ (swz << 3)]);
      }
      __builtin_amdgcn_s_setprio(1);
#pragma unroll
      for (int mi = 0; mi < 4; ++mi)
        o_acc[mi] = __builtin_amdgcn_mfma_f32_16x16x32_bf16(vf[mi], pf, o_acc[mi], 0, 0, 0);
      __builtin_amdgcn_s_setprio(0);
    }
  }
  {
    float invl = 1.f / l_run;
    ushort* orow = ao + (size_t)(b * SS + q0 + w * 16 + lr) * DD + h * 64;
#pragma unroll
    for (int mi = 0; mi < 4; ++mi) {
      ushort4v o;
#pragma unroll
      for (int i = 0; i < 4; ++i) o[i] = f2bf(o_acc[mi][i] * invl);
      *(ushort4v*)(orow + mi * 16 + lg * 4) = o;
    }
  }
}

// ---------------- residual add + layernorm (pure bf16 stream, 1 wave/row) ----------------
__global__ __launch_bounds__(64) void k_addln(ushort* __restrict__ xb,
                                              const ushort* __restrict__ y,
                                              const float* __restrict__ sc,
                                              const float* __restrict__ bi) {
  int row = blockIdx.x, l = threadIdx.x;
  int d0 = l * 12;
  ushort* xr = xb + (size_t)row * DD;
  const ushort* yr = y + (size_t)row * DD;
  ushort4v xa[3], ya[3];
#pragma unroll
  for (int j = 0; j < 3; ++j) {
    xa[j] = *(const ushort4v*)(xr + d0 + j * 4);
    ya[j] = *(const ushort4v*)(yr + d0 + j * 4);
  }
  float v[12];
  float s = 0.f;
#pragma unroll
  for (int j = 0; j < 3; ++j)
#pragma unroll
    for (int i = 0; i < 4; ++i) {
      float vv = bf2f(xa[j][i]) + bf2f(ya[j][i]);
      v[j * 4 + i] = vv;
      s += vv;
    }
  float mu = wave_sum(s);
  mu = __shfl(mu, 0) * (1.f / 768.f);
  float vs = 0.f;
#pragma unroll
  for (int i = 0; i < 12; ++i) {
    float c = v[i] - mu;
    vs += c * c;
  }
  vs = wave_sum(vs);
  float rstd = rsqrtf(__shfl(vs, 0) * (1.f / 768.f) + 1e-5f);
  float4 scv[3], biv[3];
#pragma unroll
  for (int j = 0; j < 3; ++j) {
    scv[j] = *(const float4*)(sc + d0 + j * 4);
    biv[j] = *(const float4*)(bi + d0 + j * 4);
  }
#pragma unroll
  for (int j = 0; j < 3; ++j) {
    ushort4v o;
    const float* sj = (const float*)&scv[j];
    const float* bj = (const float*)&biv[j];
#pragma unroll
    for (int i = 0; i < 4; ++i) o[i] = f2bf((v[j * 4 + i] - mu) * rstd * sj[i] + bj[i]);
    *(ushort4v*)(xr + d0 + j * 4) = o;
  }
}

// ---------------- mean pool + classifier ----------------
__global__ __launch_bounds__(256) void k_pool(const ushort* __restrict__ xb,
                                              float* __restrict__ pooled) {
  int b = blockIdx.x, chunk = blockIdx.y, t = threadIdx.x;
  float a0 = 0, a1 = 0, a2 = 0;
  for (int s2 = chunk * 128; s2 < chunk * 128 + 128; ++s2) {
    const ushort* xr = xb + (size_t)(b * SS + s2) * DD;
    a0 += bf2f(xr[t]); a1 += bf2f(xr[t + 256]); a2 += bf2f(xr[t + 512]);
  }
  atomicAdd(&pooled[b * DD + t], a0 * (1.f / 1024.f));
  atomicAdd(&pooled[b * DD + t + 256], a1 * (1.f / 1024.f));
  atomicAdd(&pooled[b * DD + t + 512], a2 * (1.f / 1024.f));
}

__global__ __launch_bounds__(64) void k_cls(const float* __restrict__ pooled,
                                            const float* __restrict__ Wc,
                                            const float* __restrict__ bc,
                                            float* __restrict__ out) {
  int idx = blockIdx.x;
  int b = idx / CC, c = idx % CC;
  int t = threadIdx.x;
  float acc = 0.f;
  for (int d0 = t; d0 < DD; d0 += 64) acc = fmaf(pooled[b * DD + d0], Wc[d0 * CC + c], acc);
  acc = wave_sum(acc);
  if (t == 0) out[b * CC + c] = acc + bc[c];
}

extern "C" void kernel_launch(void* const* d_in, const int* in_sizes, int n_in,
                              void* d_out, int out_size, void* d_ws, size_t ws_size,
                              hipStream_t stream) {
  (void)in_sizes; (void)n_in; (void)out_size; (void)ws_size;
  const int* tokens = (const int*)d_in[0];
  const float* emb = (const float*)d_in[1];
  const float* Wq = (const float*)d_in[2];
  const float* Wk = (const float*)d_in[3];
  const float* Wv = (const float*)d_in[4];
  const float* Wo = (const float*)d_in[5];
  const float* W1 = (const float*)d_in[6];
  const float* W2 = (const float*)d_in[7];
  const float* l1s = (const float*)d_in[8];
  const float* l1b = (const float*)d_in[9];
  const float* l2s = (const float*)d_in[10];
  const float* l2b = (const float*)d_in[11];
  const float* Wc = (const float*)d_in[12];
  const float* bc = (const float*)d_in[13];
  float* out = (float*)d_out;

  char* p = (char*)d_ws;
  ushort* xb = (ushort*)p;              p += (size_t)BS_ * DD * 2;
  ushort* qkvb = (ushort*)p;            // [8192][2304]
  ushort* hb = (ushort*)p;              // [8192][3072] overlay
  ushort* ao = (ushort*)(p + (size_t)BS_ * 2304 * 2);
  p += (size_t)BS_ * FF * 2;
  ushort* yb = (ushort*)p;              p += (size_t)BS_ * DD * 2;
  ushort* wt = (ushort*)p;              p += (size_t)WT_STRIDE * LL * 2;   // all 6 layers
  float* pooled = (float*)p;

  k_embed<<<BS_, 256, 0, stream>>>(tokens, emb, xb);
  k_transpose_all<<<dim3(1728, LL), 256, 0, stream>>>(Wq, Wk, Wv, Wo, W1, W2, wt);

  for (int l = 0; l < LL; ++l) {
    ushort* wqkv_t = wt + (size_t)l * WT_STRIDE;   // [2304][768]
    ushort* wo_t = wqkv_t + 2304 * 768;            // [768][768]
    ushort* w1_t = wo_t + 768 * 768;               // [3072][768]
    ushort* w2_t = w1_t + 3072 * 768;              // [768][3072]

    k_gemm_db<0, 128, 1><<<dim3(2304 / 128, BS_ / 128), 256, 0, stream>>>(xb, wqkv_t, qkvb, BS_, 2304, DD);
    k_flash<<<dim3(16, BB * HH), 256, 0, stream>>>(qkvb, ao);
    k_gemm_db<0, 64><<<dim3(DD / 64, BS_ / 128), 256, 0, stream>>>(ao, wo_t, yb, BS_, DD, DD);
    k_addln<<<BS_, 64, 0, stream>>>(xb, yb, l1s + l * DD, l1b + l * DD);
    k_gemm_db<1, 128><<<dim3(FF / 128, BS_ / 128), 256, 0, stream>>>(xb, w1_t, hb, BS_, FF, DD);
    k_gemm_db<0, 64><<<dim3(DD / 64, BS_ / 128), 256, 0, stream>>>(hb, w2_t, yb, BS_, DD, FF);
    k_addln<<<BS_, 64, 0, stream>>>(xb, yb, l2s + l * DD, l2b + l * DD);
  }

  hipMemsetAsync(pooled, 0, (size_t)BB * DD * sizeof(float), stream);
  k_pool<<<dim3(BB, 8), 256, 0, stream>>>(xb, pooled);
  k_cls<<<BB * CC, 64, 0, stream>>>(pooled, Wc, bc, out);
}

// Round 16
// 1399.333 us; speedup vs baseline: 1.0641x; 1.0221x over previous
//
#include <hip/hip_runtime.h>
#include <hip/hip_bf16.h>
#include <math.h>

#define BB 8
#define SS 1024
#define DD 768
#define HH 12
#define LL 6
#define FF 3072
#define CC 10
#define BS_ (BB * SS)   // 8192 rows

// per-layer transposed-weight block (elements)
#define WT_STRIDE (2304 * 768 + 768 * 768 + 3072 * 768 + 768 * 3072)

typedef __attribute__((ext_vector_type(8))) short short8v;       // bf16x8 MFMA frag
typedef __attribute__((ext_vector_type(4))) float f32x4;         // 16x16 MFMA acc
typedef __attribute__((ext_vector_type(8))) unsigned short ushort8v;
typedef __attribute__((ext_vector_type(4))) unsigned short ushort4v;
typedef __attribute__((ext_vector_type(2))) unsigned int uint2v;

#define CEXPQ 0.18033688f   // 0.125 * log2(e), folded into Q at the QKV epilogue

__device__ inline unsigned short f2bf(float f) {
  unsigned int u = __builtin_bit_cast(unsigned int, f);
  u += 0x7fffu + ((u >> 16) & 1u);
  return (unsigned short)(u >> 16);
}
__device__ inline float bf2f(unsigned short u) {
  return __builtin_bit_cast(float, (unsigned int)u << 16);
}
// packed f32x2 -> bf16x2 (RNE) via the HW instruction
__device__ inline unsigned int cvtpk(float lo, float hi) {
  unsigned int r;
  asm("v_cvt_pk_bf16_f32 %0, %1, %2" : "=v"(r) : "v"(lo), "v"(hi));
  return r;
}
__device__ inline void gload16(const void* g, void* l) {
  __builtin_amdgcn_global_load_lds((const __attribute__((address_space(1))) void*)g,
                                   (__attribute__((address_space(3))) void*)l, 16, 0, 0);
}

// ---------------- reduction helpers ----------------
__device__ inline float wave_sum(float v) {
#pragma unroll
  for (int off = 32; off > 0; off >>= 1) v += __shfl_down(v, off);
  return v;
}

// ---------------- embedding + sinusoidal PE (bf16 stream) ----------------
__global__ __launch_bounds__(256) void k_embed(const int* __restrict__ tokens,
                                               const float* __restrict__ emb,
                                               ushort* __restrict__ xb) {
  int row = blockIdx.x;
  int s = row & (SS - 1);
  int tok = tokens[row];
  const float* e = emb + (size_t)tok * DD;
  ushort* xbr = xb + (size_t)row * DD;
  for (int d = threadIdx.x; d < DD; d += 256) {
    float freq = expf((float)(d & ~1) * -0.0119926306f);
    float ang = (float)s * freq;
    float pe = (d & 1) ? cosf(ang) : sinf(ang);
    xbr[d] = f2bf(e[d] + pe);
  }
}

// ---------------- ALL-layer weight transpose: 64x64 tiles, transposed-LDS-store ----------------
// Load phase: coalesced float4 global reads, 16 scalar ds_writes to the
// TRANSPOSED position (bank pattern (16b+m+a)%32 = 2-way, free). Pack phase:
// row-contiguous float4 LDS reads -> cvt -> 16B global stores.
__global__ __launch_bounds__(256) void k_transpose_all(
    const float* __restrict__ Wq, const float* __restrict__ Wk,
    const float* __restrict__ Wv, const float* __restrict__ Wo,
    const float* __restrict__ W1, const float* __restrict__ W2,
    ushort* __restrict__ wt) {
  __shared__ float tile[64][65];   // [n][k] (already transposed)
  int bid = blockIdx.x;
  int lyr = blockIdx.y;
  ushort* wqkv_t = wt + (size_t)lyr * WT_STRIDE;
  ushort* wo_t = wqkv_t + 2304 * 768;
  ushort* w1_t = wo_t + 768 * 768;
  ushort* w2_t = w1_t + 3072 * 768;
  const float* W; ushort* Wt; int K, N, lb;
  if (bid < 432) {
    int m = bid / 144; lb = bid - m * 144;
    W = ((m == 0) ? Wq : (m == 1) ? Wk : Wv) + (size_t)lyr * DD * DD;
    Wt = wqkv_t + m * 768 * 768; K = 768; N = 768;
  } else if (bid < 576) {
    W = Wo + (size_t)lyr * DD * DD; Wt = wo_t; K = 768; N = 768; lb = bid - 432;
  } else if (bid < 1152) {
    W = W1 + (size_t)lyr * DD * FF; Wt = w1_t; K = 768; N = 3072; lb = bid - 576;
  } else {
    W = W2 + (size_t)lyr * FF * DD; Wt = w2_t; K = 3072; N = 768; lb = bid - 1152;
  }
  int nbk = K >> 6;
  int k0 = (lb % nbk) * 64, n0 = (lb / nbk) * 64;
  int t = threadIdx.x;
  {  // load: thread covers in[k0+r][n0+cl .. +15]; store transposed to LDS
    int r = t >> 2, cl = (t & 3) * 16;
    const float* wrow = W + (size_t)(k0 + r) * N + n0 + cl;
#pragma unroll
    for (int j = 0; j < 4; ++j) {
      float4 v = *(const float4*)(wrow + j * 4);
      tile[cl + j * 4 + 0][r] = v.x;
      tile[cl + j * 4 + 1][r] = v.y;
      tile[cl + j * 4 + 2][r] = v.z;
      tile[cl + j * 4 + 3][r] = v.w;
    }
  }
  __syncthreads();
  {  // pack: thread covers out row n0+n, cols k0+cq .. +15 (row-contig LDS reads)
    int n = t >> 2, cq = (t & 3) * 16;
    ushort8v o0, o1;
#pragma unroll
    for (int j = 0; j < 2; ++j) {
      float4 v = *(const float4*)(&tile[n][cq + j * 4]);
      o0[j * 4 + 0] = f2bf(v.x); o0[j * 4 + 1] = f2bf(v.y);
      o0[j * 4 + 2] = f2bf(v.z); o0[j * 4 + 3] = f2bf(v.w);
    }
#pragma unroll
    for (int j = 0; j < 2; ++j) {
      float4 v = *(const float4*)(&tile[n][cq + 8 + j * 4]);
      o1[j * 4 + 0] = f2bf(v.x); o1[j * 4 + 1] = f2bf(v.y);
      o1[j * 4 + 2] = f2bf(v.z); o1[j * 4 + 3] = f2bf(v.w);
    }
    ushort* orow = Wt + (size_t)(n0 + n) * K + k0 + cq;
    *(ushort8v*)(orow) = o0;
    *(ushort8v*)(orow + 8) = o1;
  }
}

// ---------------- bf16 MFMA GEMM: dbuf + counted vmcnt (T3/T4), T2 swizzle ----------------
template <int RELU, int TN, int SCALEQ = 0>
__global__ __launch_bounds__(256) void k_gemm_db(const ushort* __restrict__ A,
                                                 const ushort* __restrict__ Bt,
                                                 ushort* __restrict__ Cout,
                                                 int M, int N, int K) {
  constexpr int NF = TN / 32;            // B frags per wave
  __shared__ ushort smem[2][(128 + TN) * 64];
  int bidl = blockIdx.y * gridDim.x + blockIdx.x;
  int nwg = gridDim.x * gridDim.y;
  int cpx = nwg >> 3;
  int tid = (bidl & 7) * cpx + (bidl >> 3);
  int n0 = (tid % gridDim.x) * TN, m0 = (tid / gridDim.x) * 128;
  int t = threadIdx.x, w = t >> 6, l = t & 63;
  int wr = (w >> 1) * 64, wc = (w & 1) * (TN / 2);
  int lr = l & 15, lg = l >> 4;
  f32x4 acc[4][NF] = {};
  int sr8 = l >> 3;
  int scw = ((l & 7) ^ sr8) * 8;          // inverse-swizzled source col
  const ushort* ag = A + (size_t)(m0 + w * 8 + sr8) * K + scw;
  const ushort* bg = Bt + (size_t)(n0 + w * 8 + sr8) * K + scw;
  int nk = K >> 6;

#define STAGE_TILE(KC0, BUF)                                                     \
  {                                                                              \
    ushort* al = &smem[BUF][(w * 8) * 64];                                       \
    ushort* bl = &smem[BUF][128 * 64 + (w * 8) * 64];                            \
    _Pragma("unroll") for (int ii = 0; ii < 4; ++ii)                             \
        gload16(ag + (size_t)ii * 32 * K + (KC0), al + ii * 2048);               \
    _Pragma("unroll") for (int ii = 0; ii < TN / 32; ++ii)                       \
        gload16(bg + (size_t)ii * 32 * K + (KC0), bl + ii * 2048);               \
  }

  STAGE_TILE(0, 0);
  if (nk > 1) STAGE_TILE(64, 1);
  int rsw = lr & 7;
  for (int k = 0; k < nk; ++k) {
    if (k + 1 < nk) {
      if constexpr (TN == 128) asm volatile("s_waitcnt vmcnt(8)" ::: "memory");
      else                     asm volatile("s_waitcnt vmcnt(6)" ::: "memory");
    } else {
      asm volatile("s_waitcnt vmcnt(0)" ::: "memory");
    }
    __builtin_amdgcn_s_barrier();
    __builtin_amdgcn_sched_barrier(0);
    const ushort* As = &smem[k & 1][0];
    const ushort* Bs = &smem[k & 1][128 * 64];
    short8v af[2][4], bfr[2][NF];
#pragma unroll
    for (int ks = 0; ks < 2; ++ks) {
#pragma unroll
      for (int mi = 0; mi < 4; ++mi)
        af[ks][mi] = *(const short8v*)(As + (wr + mi * 16 + lr) * 64 + (((ks * 4 + lg) ^ rsw) << 3));
#pragma unroll
      for (int ni = 0; ni < NF; ++ni)
        bfr[ks][ni] = *(const short8v*)(Bs + (wc + ni * 16 + lr) * 64 + (((ks * 4 + lg) ^ rsw) << 3));
    }
    asm volatile("s_waitcnt lgkmcnt(0)" ::: "memory");
    __builtin_amdgcn_s_barrier();        // all waves' frag reads done: buffer free
    __builtin_amdgcn_sched_barrier(0);
    if (k + 2 < nk) STAGE_TILE((k + 2) * 64, k & 1);
    __builtin_amdgcn_s_setprio(1);
#pragma unroll
    for (int ks = 0; ks < 2; ++ks)
#pragma unroll
      for (int mi = 0; mi < 4; ++mi)
#pragma unroll
        for (int ni = 0; ni < NF; ++ni)
          acc[mi][ni] = __builtin_amdgcn_mfma_f32_16x16x32_bf16(af[ks][mi], bfr[ks][ni], acc[mi][ni], 0, 0, 0);
    __builtin_amdgcn_s_setprio(0);
  }
#undef STAGE_TILE
  __syncthreads();
  float osc = (SCALEQ && n0 < 768) ? CEXPQ : 1.0f;
  ushort* cst = &smem[0][0];
#pragma unroll
  for (int mi = 0; mi < 4; ++mi)
#pragma unroll
    for (int ni = 0; ni < NF; ++ni) {
      int cl = wc + ni * 16 + lr;
#pragma unroll
      for (int i = 0; i < 4; ++i) {
        int rl = wr + mi * 16 + lg * 4 + i;
        float v = acc[mi][ni][i];
        if (RELU) v = fmaxf(v, 0.f);
        if (SCALEQ) v *= osc;
        cst[rl * TN + (cl ^ (((rl >> 2) & 3) << 4))] = f2bf(v);
      }
    }
  __syncthreads();
  {
    int row = t >> 1, half = t & 1;
    int swr = ((row >> 2) & 3) << 4;
    ushort* crow = Cout + (size_t)(m0 + row) * N + n0 + half * (TN / 2);
#pragma unroll
    for (int c8 = 0; c8 < TN / 16; ++c8) {
      int c = half * (TN / 2) + c8 * 8;
      ushort8v vv = *(const ushort8v*)(&cst[row * TN + (c ^ swr)]);
      *(ushort8v*)(crow + c8 * 8) = vv;
    }
  }
}

// ---------------- flash attention: 16x16 MFMA, Q-tile 128, KV-tile 64 ----------------
// r12/r13 single-buffer core (best measured: 65 us). Q pre-scaled by CEXPQ.
__global__ __launch_bounds__(256) void k_flash(const ushort* __restrict__ qkv,
                                               ushort* __restrict__ ao) {
  __shared__ ushort Ks[64][64];
  __shared__ ushort Vt[64][64];
  __shared__ ushort Ps[4][32][64];
  const int LD = 2304;
  int bidl = blockIdx.y * gridDim.x + blockIdx.x;   // grid 8 x 96 = 768
  int tid = (bidl & 7) * 96 + (bidl >> 3);
  int qt = tid & 7;
  int bh = tid >> 3;
  int h = bh % HH, b = bh / HH;
  int t = threadIdx.x, w = t >> 6, l = t & 63;
  int lr = l & 15, lg = l >> 4;
  int sw = (l & 7) << 3;
  int q0 = qt * 128;
  const ushort* qbase = qkv + (size_t)(b * SS) * LD + h * 64;
  const ushort* kbase = qbase + 768;
  const ushort* vbase = qbase + 1536;
  short8v qf[2][2];
#pragma unroll
  for (int qg = 0; qg < 2; ++qg) {
    const ushort* qrow = qbase + (size_t)(q0 + w * 32 + qg * 16 + lr) * LD + lg * 8;
    qf[qg][0] = *(const short8v*)(qrow);
    qf[qg][1] = *(const short8v*)(qrow + 32);
  }
  float l_run[2] = {0.f, 0.f};
  f32x4 o_acc[2][4] = {};
  int krow_ = w * 16 + (l >> 3);
  int kcol_ = ((l & 7) * 8) ^ ((krow_ & 7) << 3);
  const ushort* kg = kbase + (size_t)krow_ * LD + kcol_;
  ushort* kl = &Ks[w * 16][0];
  int d_ = t & 7;
  int dk0 = d_ * 8;
  int kv2 = (t >> 3) * 2;
  for (int kt = 0; kt < 16; ++kt) {
    int kv0 = kt * 64;
    const ushort* vr0 = vbase + (size_t)(kv0 + kv2) * LD + dk0;
    ushort8v v0 = *(const ushort8v*)(vr0);
    ushort8v v1 = *(const ushort8v*)(vr0 + LD);
    __syncthreads();
    gload16(kg + (size_t)kv0 * LD, kl);
    gload16(kg + (size_t)(kv0 + 8) * LD, kl + 512);
#pragma unroll
    for (int i = 0; i < 8; ++i) {
      unsigned int pack = (unsigned int)v0[i] | ((unsigned int)v1[i] << 16);
      *(unsigned int*)(&Vt[dk0 + i][kv2 ^ (((i ^ d_) & 7) << 3)]) = pack;
    }
    __syncthreads();
    short8v kf[4][2];
#pragma unroll
    for (int mi = 0; mi < 4; ++mi) {
      int kvr = mi * 16 + lr;
      kf[mi][0] = *(const short8v*)(&Ks[kvr][(lg * 8) ^ sw]);
      kf[mi][1] = *(const short8v*)(&Ks[kvr][(32 + lg * 8) ^ sw]);
    }
    f32x4 s[2][4] = {};
    __builtin_amdgcn_s_setprio(1);
#pragma unroll
    for (int mi = 0; mi < 4; ++mi)
#pragma unroll
      for (int qg = 0; qg < 2; ++qg) {
        s[qg][mi] = __builtin_amdgcn_mfma_f32_16x16x32_bf16(kf[mi][0], qf[qg][0], s[qg][mi], 0, 0, 0);
        s[qg][mi] = __builtin_amdgcn_mfma_f32_16x16x32_bf16(kf[mi][1], qf[qg][1], s[qg][mi], 0, 0, 0);
      }
    __builtin_amdgcn_s_setprio(0);
#pragma unroll
    for (int qg = 0; qg < 2; ++qg) {
      float psum = 0.f;
#pragma unroll
      for (int mi = 0; mi < 4; ++mi) {
        float p0 = exp2f(s[qg][mi][0]);
        float p1 = exp2f(s[qg][mi][1]);
        float p2 = exp2f(s[qg][mi][2]);
        float p3 = exp2f(s[qg][mi][3]);
        psum += (p0 + p1) + (p2 + p3);
        uint2v pp;
        pp.x = cvtpk(p0, p1);
        pp.y = cvtpk(p2, p3);
        *(uint2v*)(&Ps[w][qg * 16 + lr][(mi * 16 + lg * 4) ^ ((lr & 7) << 3)]) = pp;
      }
      psum += __shfl_xor(psum, 16);
      psum += __shfl_xor(psum, 32);
      l_run[qg] += psum;
    }
#pragma unroll
    for (int ks = 0; ks < 2; ++ks) {
      short8v pf[2];
      pf[0] = *(const short8v*)(&Ps[w][lr][(ks * 32 + lg * 8) ^ sw]);
      pf[1] = *(const short8v*)(&Ps[w][16 + lr][(ks * 32 + lg * 8) ^ sw]);
      short8v vf[4];
#pragma unroll
      for (int mi = 0; mi < 4; ++mi) {
        int swz = ((lr & 7) ^ (mi * 2 + (lr >> 3))) & 7;
        vf[mi] = *(const short8v*)(&Vt[mi * 16 + lr][(ks * 32 + lg * 8) ^ (swz << 3)]);
      }
      __builtin_amdgcn_s_setprio(1);
#pragma unroll
      for (int mi = 0; mi < 4; ++mi)
#pragma unroll
        for (int qg = 0; qg < 2; ++qg)
          o_acc[qg][mi] = __builtin_amdgcn_mfma_f32_16x16x32_bf16(vf[mi], pf[qg], o_acc[qg][mi], 0, 0, 0);
      __builtin_amdgcn_s_setprio(0);
    }
  }
#pragma unroll
  for (int qg = 0; qg < 2; ++qg) {
    float invl = 1.f / l_run[qg];
    ushort* orow = ao + (size_t)(b * SS + q0 + w * 32 + qg * 16 + lr) * DD + h * 64;
#pragma unroll
    for (int mi = 0; mi < 4; ++mi) {
      ushort4v o;
#pragma unroll
      for (int i = 0; i < 4; ++i) o[i] = f2bf(o_acc[qg][mi][i] * invl);
      *(ushort4v*)(orow + mi * 16 + lg * 4) = o;
    }
  }
}

// ---------------- residual add + layernorm (pure bf16 stream, 1 wave/row) ----------------
__global__ __launch_bounds__(64) void k_addln(ushort* __restrict__ xb,
                                              const ushort* __restrict__ y,
                                              const float* __restrict__ sc,
                                              const float* __restrict__ bi) {
  int row = blockIdx.x, l = threadIdx.x;
  int d0 = l * 12;
  ushort* xr = xb + (size_t)row * DD;
  const ushort* yr = y + (size_t)row * DD;
  ushort4v xa[3], ya[3];
#pragma unroll
  for (int j = 0; j < 3; ++j) {
    xa[j] = *(const ushort4v*)(xr + d0 + j * 4);
    ya[j] = *(const ushort4v*)(yr + d0 + j * 4);
  }
  float v[12];
  float s = 0.f;
#pragma unroll
  for (int j = 0; j < 3; ++j)
#pragma unroll
    for (int i = 0; i < 4; ++i) {
      float vv = bf2f(xa[j][i]) + bf2f(ya[j][i]);
      v[j * 4 + i] = vv;
      s += vv;
    }
  float mu = wave_sum(s);
  mu = __shfl(mu, 0) * (1.f / 768.f);
  float vs = 0.f;
#pragma unroll
  for (int i = 0; i < 12; ++i) {
    float c = v[i] - mu;
    vs += c * c;
  }
  vs = wave_sum(vs);
  float rstd = rsqrtf(__shfl(vs, 0) * (1.f / 768.f) + 1e-5f);
  float4 scv[3], biv[3];
#pragma unroll
  for (int j = 0; j < 3; ++j) {
    scv[j] = *(const float4*)(sc + d0 + j * 4);
    biv[j] = *(const float4*)(bi + d0 + j * 4);
  }
#pragma unroll
  for (int j = 0; j < 3; ++j) {
    ushort4v o;
    const float* sj = (const float*)&scv[j];
    const float* bj = (const float*)&biv[j];
#pragma unroll
    for (int i = 0; i < 4; ++i) o[i] = f2bf((v[j * 4 + i] - mu) * rstd * sj[i] + bj[i]);
    *(ushort4v*)(xr + d0 + j * 4) = o;
  }
}

// ---------------- mean pool + classifier ----------------
__global__ __launch_bounds__(256) void k_pool(const ushort* __restrict__ xb,
                                              float* __restrict__ pooled) {
  int b = blockIdx.x, chunk = blockIdx.y, t = threadIdx.x;
  float a0 = 0, a1 = 0, a2 = 0;
  for (int s2 = chunk * 128; s2 < chunk * 128 + 128; ++s2) {
    const ushort* xr = xb + (size_t)(b * SS + s2) * DD;
    a0 += bf2f(xr[t]); a1 += bf2f(xr[t + 256]); a2 += bf2f(xr[t + 512]);
  }
  atomicAdd(&pooled[b * DD + t], a0 * (1.f / 1024.f));
  atomicAdd(&pooled[b * DD + t + 256], a1 * (1.f / 1024.f));
  atomicAdd(&pooled[b * DD + t + 512], a2 * (1.f / 1024.f));
}

__global__ __launch_bounds__(64) void k_cls(const float* __restrict__ pooled,
                                            const float* __restrict__ Wc,
                                            const float* __restrict__ bc,
                                            float* __restrict__ out) {
  int idx = blockIdx.x;
  int b = idx / CC, c = idx % CC;
  int t = threadIdx.x;
  float acc = 0.f;
  for (int d0 = t; d0 < DD; d0 += 64) acc = fmaf(pooled[b * DD + d0], Wc[d0 * CC + c], acc);
  acc = wave_sum(acc);
  if (t == 0) out[b * CC + c] = acc + bc[c];
}

extern "C" void kernel_launch(void* const* d_in, const int* in_sizes, int n_in,
                              void* d_out, int out_size, void* d_ws, size_t ws_size,
                              hipStream_t stream) {
  (void)in_sizes; (void)n_in; (void)out_size; (void)ws_size;
  const int* tokens = (const int*)d_in[0];
  const float* emb = (const float*)d_in[1];
  const float* Wq = (const float*)d_in[2];
  const float* Wk = (const float*)d_in[3];
  const float* Wv = (const float*)d_in[4];
  const float* Wo = (const float*)d_in[5];
  const float* W1 = (const float*)d_in[6];
  const float* W2 = (const float*)d_in[7];
  const float* l1s = (const float*)d_in[8];
  const float* l1b = (const float*)d_in[9];
  const float* l2s = (const float*)d_in[10];
  const float* l2b = (const float*)d_in[11];
  const float* Wc = (const float*)d_in[12];
  const float* bc = (const float*)d_in[13];
  float* out = (float*)d_out;

  char* p = (char*)d_ws;
  ushort* xb = (ushort*)p;              p += (size_t)BS_ * DD * 2;
  ushort* qkvb = (ushort*)p;            // [8192][2304]
  ushort* hb = (ushort*)p;              // [8192][3072] overlay
  ushort* ao = (ushort*)(p + (size_t)BS_ * 2304 * 2);
  p += (size_t)BS_ * FF * 2;
  ushort* yb = (ushort*)p;              p += (size_t)BS_ * DD * 2;
  ushort* wt = (ushort*)p;              p += (size_t)WT_STRIDE * LL * 2;   // all 6 layers
  float* pooled = (float*)p;

  k_embed<<<BS_, 256, 0, stream>>>(tokens, emb, xb);
  k_transpose_all<<<dim3(1728, LL), 256, 0, stream>>>(Wq, Wk, Wv, Wo, W1, W2, wt);

  for (int l = 0; l < LL; ++l) {
    ushort* wqkv_t = wt + (size_t)l * WT_STRIDE;   // [2304][768]
    ushort* wo_t = wqkv_t + 2304 * 768;            // [768][768]
    ushort* w1_t = wo_t + 768 * 768;               // [3072][768]
    ushort* w2_t = w1_t + 3072 * 768;              // [768][3072]

    k_gemm_db<0, 128, 1><<<dim3(2304 / 128, BS_ / 128), 256, 0, stream>>>(xb, wqkv_t, qkvb, BS_, 2304, DD);
    k_flash<<<dim3(8, BB * HH), 256, 0, stream>>>(qkvb, ao);
    k_gemm_db<0, 64><<<dim3(DD / 64, BS_ / 128), 256, 0, stream>>>(ao, wo_t, yb, BS_, DD, DD);
    k_addln<<<BS_, 64, 0, stream>>>(xb, yb, l1s + l * DD, l1b + l * DD);
    k_gemm_db<1, 128><<<dim3(FF / 128, BS_ / 128), 256, 0, stream>>>(xb, w1_t, hb, BS_, FF, DD);
    k_gemm_db<0, 64><<<dim3(DD / 64, BS_ / 128), 256, 0, stream>>>(hb, w2_t, yb, BS_, DD, FF);
    k_addln<<<BS_, 64, 0, stream>>>(xb, yb, l2s + l * DD, l2b + l * DD);
  }

  hipMemsetAsync(pooled, 0, (size_t)BB * DD * sizeof(float), stream);
  k_pool<<<dim3(BB, 8), 256, 0, stream>>>(xb, pooled);
  k_cls<<<BB * CC, 64, 0, stream>>>(pooled, Wc, bc, out);
}